// Round 9
// baseline (283.879 us; speedup 1.0000x reference)
//
#include <hip/hip_runtime.h>

// NeighbourCovariance: per vertex v, gather K=40 neighbors, weight features by
// exp(-10*distsq), compute per-feature weighted mean (C=3) and covariance (3x3).
// Output layout per vertex: [cov (F*9)] ++ [means (F*3)] = 384 floats.
//
// R11: SPATIAL footprint split by XCD. R10's temporal lo/hi split failed (FETCH
// flat at 291 MB) because block phases drift: late blocks run pass A while early
// blocks run pass B, so each L2 still sees lo+hi = 6.4 MB > 4 MB. Fix: enforce
// the split in SPACE. Grid = 2x chunks; dispatcher round-robins blocks over
// XCDs (blockIdx%8), so blocks with xcd 0-3 process ONLY plane lo (3.2 MB) and
// xcd 4-7 ONLY plane hi. Each per-XCD L2 then holds one whole plane -> gather
// capacity misses structurally vanish, gather becomes L2-hit and leaves the
// fabric. Phase 1 (streams/exp/coords) runs twice (+32 MB, ~1 us) -- cheap vs
// the ~150-180 MB of miss fill removed. If the XCD mapping ever changes, only
// locality (speed) is affected, never correctness.
// Also: R9/R10's persistent 1.2M bank conflicts were the STAGE WRITES
// (vloc*192 + fl*9; 192 = 0 mod 32 -> 4-way vloc aliasing), not the k-loop
// reads. Stage stride padded 192 -> 196 floats (49 f4, 16B-aligned).
//
//  Phase 1: 640 (v,k) pairs; NT stream loads of nidx/distsq, one exp per pair,
//           coord gather; stage (w,x,y,z) + j*16 plane row offset in LDS.
//  Phase 2: lane=(v, f-slot 0..15); 40 x {b128 broadcast moment read + 32B
//           fp16 plane-row gather (L2-hit) + 18 VALU}.
//  Phase 3: stage half-output in LDS (padded), coalesced 16B NT writeback of
//           this half's disjoint cov/means f4 regions.
//
// LDS: wxyz 16*41*16=10496 + joff 2560 + stage 16*49*16=12544 = 25600 B
//      -> 6 blocks/CU, 24 waves/CU (R5: 24 waves == 32 here).
// f32 fallback (R4 structure, 95 us known-good) if ws too small.

constexpr int K = 40;
constexpr int C = 3;
constexpr int F = 32;
constexpr int FH = 16;                        // features per half-plane
constexpr float EPS = 1e-3f;
constexpr float DIST_SCALE = 10.0f;
constexpr int OUT_PER_V = F * C * C + F * C;  // 384 floats = 96 float4
constexpr int VPB = 16;                       // vertices per block
constexpr int PAIRS = VPB * K;                // 640
constexpr int WSTRIDE = K + 1;                // padded moment stride
constexpr int VSTRIDE4 = 49;                  // stage f4 per vertex (196 floats)

typedef float    floatx4 __attribute__((ext_vector_type(4)));  // nt-store ok
typedef float    f32x8   __attribute__((ext_vector_type(8)));
typedef _Float16 f16x8   __attribute__((ext_vector_type(8)));

// ---- Pass 0: features f32 -> two fp16 half-planes (3.2 MB each) ----
__global__ __launch_bounds__(256) void cvt_kernel(
    const float* __restrict__ in, _Float16* __restrict__ lo,
    _Float16* __restrict__ hi, int n4)   // n4 = V*4
{
    const int i = blockIdx.x * 256 + threadIdx.x;
    if (i >= n4) return;
    const int v = i >> 2, q = i & 3;
    const f32x8 x = __builtin_nontemporal_load((const f32x8*)in + i);
    const f16x8 o = __builtin_convertvector(x, f16x8);
    _Float16* dst = (q < 2 ? lo : hi) + (size_t)v * FH + (q & 1) * 8;
    *(f16x8*)dst = o;   // cached store: re-read by main kernel
}

// ---- Main kernel: one feature half-plane per block, XCD-pinned ----
__global__ __launch_bounds__(256) void neighcov_xcd(
    const float* __restrict__ coords,     // V x 3
    const float* __restrict__ distsq,     // V x K
    const _Float16* __restrict__ plane_lo,// V x 16
    const _Float16* __restrict__ plane_hi,// V x 16
    const int*   __restrict__ nidx,       // V x K
    float* __restrict__ out,              // V x 384
    int V, int nchunks)
{
    __shared__ float4  s_wxyz[VPB * WSTRIDE];   // (w,x,y,z) padded     10496 B
    __shared__ int     s_joff[PAIRS];           // j*16 plane offset     2560 B
    __shared__ floatx4 s_stage[VPB * VSTRIDE4]; // half-output, padded  12544 B

    // XCD pinning: dispatcher round-robins blockIdx over 8 XCDs.
    const int b    = blockIdx.x;
    const int xcd  = b & 7;
    const int half = xcd >> 2;                 // XCD 0-3 -> lo, 4-7 -> hi
    const int ord  = (b >> 3) * 4 + (xcd & 3); // chunk ordinal within half
    if (ord >= nchunks) return;                // uniform per block: safe
    const int vbase = ord * VPB;

    const int tid = threadIdx.x;
    const long long total_pairs = (long long)V * K;

    // ---- Phase 1: stage weights/coords, 640 pairs ----
    for (int p = tid; p < PAIRS; p += 256) {
        const long long gp = (long long)vbase * K + p;
        int idx = -1;
        float d = 0.f;
        if (gp < total_pairs) {
            idx = __builtin_nontemporal_load(nidx + gp);    // coalesced, single-use
            d   = __builtin_nontemporal_load(distsq + gp);  // coalesced, single-use
        }
        const bool valid = (idx >= 0);
        const int j = valid ? idx : 0;
        const float w = valid ? __expf(-DIST_SCALE * d) : 0.f;  // w==0 = invalid
        const float x = coords[(size_t)j * 3 + 0];
        const float y = coords[(size_t)j * 3 + 1];
        const float z = coords[(size_t)j * 3 + 2];
        const int vloc = p / K, k = p - vloc * K;
        s_wxyz[vloc * WSTRIDE + k] = make_float4(w, x, y, z);
        s_joff[p] = j * FH;
    }
    __syncthreads();

    // ---- Phase 2: lane = (vertex, feature-slot); this block's half only ----
    const int fl   = tid & 15;   // feature slot within half
    const int vloc = tid >> 4;   // 0..15
    const float4* wp = &s_wxyz[vloc * WSTRIDE];
    const int*    jp = &s_joff[vloc * K];
    const _Float16* __restrict__ plane = half ? plane_hi : plane_lo;

    float wsum = 0.f;
    float m0 = 0.f, m1 = 0.f, m2 = 0.f;
    float s00 = 0.f, s01 = 0.f, s02 = 0.f, s11 = 0.f, s12 = 0.f, s22 = 0.f;

    #pragma unroll 8
    for (int k = 0; k < K; ++k) {
        const float4 q = wp[k];         // b128 broadcast; 4 groups on disjoint bank quads
        const int jo   = jp[k];         // b32 broadcast; 4 distinct banks
        const float feat = (float)plane[jo + fl];  // 32B plane-row gather (L2-hit)
        const float fw = q.x * feat;    // w==0 encodes invalid neighbor
        const float x = q.y, y = q.z, z = q.w;
        const float fx = fw * x, fy = fw * y, fz = fw * z;
        wsum += fw;
        m0 += fx;        m1 += fy;        m2 += fz;
        s00 += fx * x;   s01 += fx * y;   s02 += fx * z;
        s11 += fy * y;   s12 += fy * z;   s22 += fz * z;
    }

    const float inv = 1.f / (wsum + EPS);
    const float mu0 = m0 * inv, mu1 = m1 * inv, mu2 = m2 * inv;
    const float c00 = s00 * inv - mu0 * mu0;
    const float c01 = s01 * inv - mu0 * mu1;
    const float c02 = s02 * inv - mu0 * mu2;
    const float c11 = s11 * inv - mu1 * mu1;
    const float c12 = s12 * inv - mu1 * mu2;
    const float c22 = s22 * inv - mu2 * mu2;

    // Stage this half's results. Stride 196: bank = (4*vloc + 9*fl) mod 32,
    // near-uniform over 64 lanes -> ~2-way (free); was 4-way at stride 192.
    float* s_out = (float*)s_stage;
    float* so = s_out + vloc * (VSTRIDE4 * 4) + fl * 9;
    so[0] = c00; so[1] = c01; so[2] = c02;
    so[3] = c01; so[4] = c11; so[5] = c12;
    so[6] = c02; so[7] = c12; so[8] = c22;
    float* sm = s_out + vloc * (VSTRIDE4 * 4) + 144 + fl * 3;
    sm[0] = mu0; sm[1] = mu1; sm[2] = mu2;

    __syncthreads();

    // ---- Phase 3: coalesced NT writeback of this half's disjoint regions ----
    // Per vertex (96 f4): cov half h -> f4 [36h, 36h+36); means -> [72+12h, +12).
    const int rem_v = V - vbase;          // >= 1
    floatx4* o4 = (floatx4*)(out + (size_t)vbase * OUT_PER_V);
    #pragma unroll
    for (int g = tid; g < VPB * 48; g += 256) {
        const int v = g / 48;
        const int r = g - v * 48;
        if (v < rem_v) {
            const int dst = v * 96 + (r < 36 ? half * 36 + r
                                             : 72 + half * 12 + (r - 36));
            __builtin_nontemporal_store(s_stage[v * VSTRIDE4 + r], o4 + dst);
        }
    }
}

// ---- Fallback: R4 structure, f32 features (95 us known-good) ----
constexpr int VPB8 = 8;
constexpr int PAIRS8 = VPB8 * K;              // 320
constexpr int OUT_F4_8 = VPB8 * OUT_PER_V / 4;// 768

__global__ __launch_bounds__(256) void neighcov_f32(
    const float* __restrict__ coords, const float* __restrict__ distsq,
    const float* __restrict__ features, const int* __restrict__ nidx,
    float* __restrict__ out, int V)
{
    __shared__ float4  s_wxyz[PAIRS8];
    __shared__ int     s_joff[PAIRS8];
    __shared__ floatx4 s_out4[OUT_F4_8];

    const int tid   = threadIdx.x;
    const int vbase = blockIdx.x * VPB8;
    const long long total_pairs = (long long)V * K;

    #pragma unroll
    for (int p = tid; p < PAIRS8; p += 256) {
        const long long gp = (long long)vbase * K + p;
        int idx = -1; float d = 0.f;
        if (gp < total_pairs) {
            idx = __builtin_nontemporal_load(nidx + gp);
            d   = __builtin_nontemporal_load(distsq + gp);
        }
        const bool valid = (idx >= 0);
        const int j = valid ? idx : 0;
        const float w = valid ? __expf(-DIST_SCALE * d) : 0.f;
        s_wxyz[p] = make_float4(w, coords[(size_t)j * 3 + 0],
                                coords[(size_t)j * 3 + 1], coords[(size_t)j * 3 + 2]);
        s_joff[p] = j * F;
    }
    __syncthreads();

    const int f = tid & (F - 1), vloc = tid >> 5;
    const float4* wp = &s_wxyz[vloc * K];
    const int*    jp = &s_joff[vloc * K];

    float wsum = 0.f, m0 = 0.f, m1 = 0.f, m2 = 0.f;
    float s00 = 0.f, s01 = 0.f, s02 = 0.f, s11 = 0.f, s12 = 0.f, s22 = 0.f;
    #pragma unroll 8
    for (int k = 0; k < K; ++k) {
        const float4 q = wp[k];
        const float feat = features[jp[k] + f];
        const float fw = q.x * feat;
        const float x = q.y, y = q.z, z = q.w;
        const float fx = fw * x, fy = fw * y, fz = fw * z;
        wsum += fw; m0 += fx; m1 += fy; m2 += fz;
        s00 += fx * x; s01 += fx * y; s02 += fx * z;
        s11 += fy * y; s12 += fy * z; s22 += fz * z;
    }
    const float inv = 1.f / (wsum + EPS);
    const float mu0 = m0 * inv, mu1 = m1 * inv, mu2 = m2 * inv;
    float* s_out = (float*)s_out4;
    float* so = s_out + vloc * OUT_PER_V + f * 9;
    so[0] = s00 * inv - mu0 * mu0; so[1] = s01 * inv - mu0 * mu1;
    so[2] = s02 * inv - mu0 * mu2; so[3] = so[1];
    so[4] = s11 * inv - mu1 * mu1; so[5] = s12 * inv - mu1 * mu2;
    so[6] = so[2]; so[7] = so[5]; so[8] = s22 * inv - mu2 * mu2;
    float* sm = s_out + vloc * OUT_PER_V + F * 9 + f * 3;
    sm[0] = mu0; sm[1] = mu1; sm[2] = mu2;
    __syncthreads();

    const int rem_v = V - vbase;
    const int lim_f4 = (rem_v >= VPB8) ? OUT_F4_8 : rem_v * (OUT_PER_V / 4);
    floatx4* o4 = (floatx4*)(out + (size_t)vbase * OUT_PER_V);
    #pragma unroll
    for (int g = tid; g < OUT_F4_8; g += 256)
        if (g < lim_f4) __builtin_nontemporal_store(s_out4[g], o4 + g);
}

extern "C" void kernel_launch(void* const* d_in, const int* in_sizes, int n_in,
                              void* d_out, int out_size, void* d_ws, size_t ws_size,
                              hipStream_t stream) {
    const float* coords   = (const float*)d_in[0];
    const float* distsq   = (const float*)d_in[1];
    const float* features = (const float*)d_in[2];
    const int*   nidx     = (const int*)d_in[3];
    float* out = (float*)d_out;

    const int V = in_sizes[0] / C;            // coordinates is V x 3

    const size_t plane_bytes = (size_t)V * FH * sizeof(_Float16);
    if (ws_size >= 2 * plane_bytes) {
        _Float16* lo = (_Float16*)d_ws;
        _Float16* hi = lo + (size_t)V * FH;
        const int n4 = V * 4;
        cvt_kernel<<<(n4 + 255) / 256, 256, 0, stream>>>(features, lo, hi, n4);
        const int nchunks = (V + VPB - 1) / VPB;          // 6250
        const int grid = 8 * ((nchunks + 3) / 4);         // >= nchunks per half
        neighcov_xcd<<<grid, 256, 0, stream>>>(
            coords, distsq, lo, hi, nidx, out, V, nchunks);
    } else {
        const int blocks = (V + VPB8 - 1) / VPB8;
        neighcov_f32<<<blocks, 256, 0, stream>>>(
            coords, distsq, features, nidx, out, V);
    }
}

// Round 10
// 247.691 us; speedup vs baseline: 1.1461x; 1.1461x over previous
//
#include <hip/hip_runtime.h>

// NeighbourCovariance: per vertex v, gather K=40 neighbors, weight features by
// exp(-10*distsq), compute per-feature weighted mean (C=3) and covariance (3x3).
// Output layout per vertex: [cov (F*9)] ++ [means (F*3)] = 384 floats.
//
// R12: stack the two proven-orthogonal wins; drop the proven losses.
//  - fp16 feature gather (R4->R8: -9 us, single 6.4 MB plane, one pass).
//  - R5 moment-precompute (VALU busy 57->37 us proven; was masked at f32
//    because f32 was traffic-limited at ~96 us; fp16 runs at 3.4 TB/s < limit
//    so the VALU cut should now show through).
//  - R4/R8's 32-feature lane mapping (measured ZERO bank conflicts; the
//    16-slot mapping of R9-R11 cost 1.2-1.4M).
//  - NO XCD/plane split (R11: -174 MB fetch but +13 us -- traffic is not the
//    binding constraint at the fp16 point; doubled phase-1 cost dominates).
//
//  Pass 0: cvt features f32 -> fp16 [V][32] in d_ws (~6 us).
//  Phase 1: 320 (v,k) pairs; NT stream loads of nidx/distsq, one exp; coords
//           gather; per-pair moments (w,wx,wy,wz,wxx,wxy,wxz,wyy,wyz,wzz)+joff
//           staged in LDS.
//  Phase 2: lane=(v, f 0..31); 40 x {5 broadcast v2f LDS reads + 64B fp16 row
//           gather + cvt + 5 v_pk_fma_f32}.
//  Phase 3: stage output in LDS (R4 mapping, conflict-free) -> coalesced 16B
//           NT writeback.
//
// LDS: s_a 5120 + s_b 5120 + s_c 2560 + s_joff 1280 + s_out 12288 = 26368 B
//      -> 6 blocks/CU, 24 waves/CU (R5: 24 == 32 waves for this kernel).
// f32 fallback via template if ws too small.

constexpr int K = 40;
constexpr int C = 3;
constexpr int F = 32;
constexpr float EPS = 1e-3f;
constexpr float DIST_SCALE = 10.0f;
constexpr int OUT_PER_V = F * C * C + F * C; // 384
constexpr int VPB = 8;                        // vertices per 256-thread block
constexpr int PAIRS = VPB * K;                // 320
constexpr int OUT_DW = VPB * OUT_PER_V;       // 3072 dwords staged per block
constexpr int OUT_F4 = OUT_DW / 4;            // 768 float4 per block

typedef float    floatx4 __attribute__((ext_vector_type(4)));  // nt-store ok
typedef float    v2f     __attribute__((ext_vector_type(2)));  // v_pk_fma_f32
typedef float    f32x8   __attribute__((ext_vector_type(8)));
typedef _Float16 f16x8   __attribute__((ext_vector_type(8)));

// ---- Pass 0: features f32 -> fp16 (12.8 MB -> 6.4 MB), 8 elems/thread ----
__global__ __launch_bounds__(256) void cvt_kernel(
    const float* __restrict__ in, _Float16* __restrict__ out16, int n8)
{
    const int i = blockIdx.x * 256 + threadIdx.x;
    if (i < n8) {
        const f32x8 v = __builtin_nontemporal_load((const f32x8*)in + i);
        const f16x8 o = __builtin_convertvector(v, f16x8);
        *((f16x8*)out16 + i) = o;   // cached store: re-read by main kernel
    }
}

// ---- Main kernel, templated on feature type ----
template <typename FT>
__global__ __launch_bounds__(256) void neighcov_kernel(
    const float* __restrict__ coords,    // V x 3
    const float* __restrict__ distsq,    // V x K
    const FT*    __restrict__ features,  // V x F (f32 or fp16)
    const int*   __restrict__ nidx,      // V x K
    float* __restrict__ out,             // V x 384
    int V)
{
    __shared__ float4  s_a[PAIRS];      // (w,   wx,  wy,  wz ) per (v,k)
    __shared__ float4  s_b[PAIRS];      // (wxx, wxy, wxz, wyy)
    __shared__ v2f     s_c[PAIRS];      // (wyz, wzz)
    __shared__ int     s_joff[PAIRS];   // j*F element offset into features
    __shared__ floatx4 s_out4[OUT_F4];  // staged output (16B-aligned)

    const int tid   = threadIdx.x;
    const int vbase = blockIdx.x * VPB;
    const long long total_pairs = (long long)V * K;

    // ---- Phase 1: stage weighted coordinate moments, 320 pairs ----
    #pragma unroll
    for (int p = tid; p < PAIRS; p += 256) {
        const long long gp = (long long)vbase * K + p;
        int idx = -1;
        float d = 0.f;
        if (gp < total_pairs) {
            idx = __builtin_nontemporal_load(nidx + gp);    // coalesced, single-use
            d   = __builtin_nontemporal_load(distsq + gp);  // coalesced, single-use
        }
        const bool valid = (idx >= 0);
        const int j = valid ? idx : 0;
        const float w = valid ? __expf(-DIST_SCALE * d) : 0.f;  // w==0 = invalid
        const float x = coords[(size_t)j * 3 + 0];
        const float y = coords[(size_t)j * 3 + 1];
        const float z = coords[(size_t)j * 3 + 2];
        const float wx = w * x, wy = w * y, wz = w * z;
        s_a[p] = make_float4(w, wx, wy, wz);
        s_b[p] = make_float4(wx * x, wx * y, wx * z, wy * y);
        s_c[p] = (v2f){wy * z, wz * z};
        s_joff[p] = j * F;
    }
    __syncthreads();

    // ---- Phase 2: lane=(v, f); 5 pk_fma per neighbor (R5 body, 0 conflicts) ----
    const int f    = tid & (F - 1);
    const int vloc = tid >> 5;

    const v2f* a2 = (const v2f*)(s_a + vloc * K);  // pairs (w,wx) (wy,wz)
    const v2f* b2 = (const v2f*)(s_b + vloc * K);  // pairs (wxx,wxy) (wxz,wyy)
    const v2f* c2 = s_c + vloc * K;                // pair  (wyz,wzz)
    const int* jp = s_joff + vloc * K;

    v2f acc0 = {0.f, 0.f};  // (wsum, m0)
    v2f acc1 = {0.f, 0.f};  // (m1,   m2)
    v2f acc2 = {0.f, 0.f};  // (s00,  s01)
    v2f acc3 = {0.f, 0.f};  // (s02,  s11)
    v2f acc4 = {0.f, 0.f};  // (s12,  s22)

    #pragma unroll 8
    for (int k = 0; k < K; ++k) {
        const v2f a_lo = a2[2 * k];      // broadcast LDS reads (merge to b128)
        const v2f a_hi = a2[2 * k + 1];
        const v2f b_lo = b2[2 * k];
        const v2f b_hi = b2[2 * k + 1];
        const v2f cc   = c2[k];
        const float feat = (float)features[jp[k] + f];  // coalesced row gather
        const v2f fv = {feat, feat};
        acc0 = __builtin_elementwise_fma(a_lo, fv, acc0);
        acc1 = __builtin_elementwise_fma(a_hi, fv, acc1);
        acc2 = __builtin_elementwise_fma(b_lo, fv, acc2);
        acc3 = __builtin_elementwise_fma(b_hi, fv, acc3);
        acc4 = __builtin_elementwise_fma(cc,   fv, acc4);
    }

    const float wsum = acc0.x, m0 = acc0.y, m1 = acc1.x, m2 = acc1.y;
    const float s00 = acc2.x, s01 = acc2.y, s02 = acc3.x;
    const float s11 = acc3.y, s12 = acc4.x, s22 = acc4.y;

    const float inv = 1.f / (wsum + EPS);
    const float mu0 = m0 * inv, mu1 = m1 * inv, mu2 = m2 * inv;
    const float c00 = s00 * inv - mu0 * mu0;
    const float c01 = s01 * inv - mu0 * mu1;
    const float c02 = s02 * inv - mu0 * mu2;
    const float c11 = s11 * inv - mu1 * mu1;
    const float c12 = s12 * inv - mu1 * mu2;
    const float c22 = s22 * inv - mu2 * mu2;

    // Stage results in LDS. R4 mapping: f*9 mod 32 bijective over 32 banks,
    // 2 vloc groups -> free 2-way. Measured 0 conflicts in R2-R8.
    float* s_out = (float*)s_out4;
    float* so = s_out + vloc * OUT_PER_V + f * 9;
    so[0] = c00; so[1] = c01; so[2] = c02;
    so[3] = c01; so[4] = c11; so[5] = c12;
    so[6] = c02; so[7] = c12; so[8] = c22;
    float* sm = s_out + vloc * OUT_PER_V + F * 9 + f * 3;
    sm[0] = mu0; sm[1] = mu1; sm[2] = mu2;

    __syncthreads();

    // ---- Phase 3: coalesced non-temporal 16B writeback ----
    const int rem_v  = V - vbase;  // >= 1
    const int lim_f4 = (rem_v >= VPB) ? OUT_F4 : rem_v * (OUT_PER_V / 4);
    floatx4* o4 = (floatx4*)(out + (size_t)vbase * OUT_PER_V);
    #pragma unroll
    for (int g = tid; g < OUT_F4; g += 256) {
        if (g < lim_f4) {
            __builtin_nontemporal_store(s_out4[g], o4 + g);  // contiguous b128 LDS read
        }
    }
}

extern "C" void kernel_launch(void* const* d_in, const int* in_sizes, int n_in,
                              void* d_out, int out_size, void* d_ws, size_t ws_size,
                              hipStream_t stream) {
    const float* coords   = (const float*)d_in[0];
    const float* distsq   = (const float*)d_in[1];
    const float* features = (const float*)d_in[2];
    const int*   nidx     = (const int*)d_in[3];
    float* out = (float*)d_out;

    const int V = in_sizes[0] / C;            // coordinates is V x 3
    const int blocks = (V + VPB - 1) / VPB;   // 8 vertices per 256-thread block

    const size_t need = (size_t)V * F * sizeof(_Float16);
    const int nelem = V * F;
    if (ws_size >= need && (nelem & 7) == 0) {
        _Float16* feat16 = (_Float16*)d_ws;
        const int n8 = nelem / 8;
        cvt_kernel<<<(n8 + 255) / 256, 256, 0, stream>>>(features, feat16, n8);
        neighcov_kernel<_Float16><<<blocks, 256, 0, stream>>>(
            coords, distsq, feat16, nidx, out, V);
    } else {
        neighcov_kernel<float><<<blocks, 256, 0, stream>>>(
            coords, distsq, features, nidx, out, V);
    }
}